// Round 19
// baseline (215.509 us; speedup 1.0000x reference)
//
#include <hip/hip_runtime.h>
#include <math.h>

#define BATCH 4
#define SEQ 2048
#define FEAT 512
#define NHEADS 8
#define HD 64
#define NROWS (BATCH*SEQ)   // 8192
#define QSCALE 0.18033688011112042f   // log2(e)/8

typedef __attribute__((ext_vector_type(4)))  float f32x4;
typedef __attribute__((ext_vector_type(16))) float f32x16;
typedef __attribute__((ext_vector_type(8)))  short s16x8;
typedef __attribute__((ext_vector_type(8)))  unsigned short u16x8;
typedef __attribute__((ext_vector_type(4)))  unsigned int u32x4;

#if __has_builtin(__builtin_amdgcn_exp2f)
#define EX2(x) __builtin_amdgcn_exp2f(x)
#else
#define EX2(x) __expf((x) * 0.6931471805599453f)
#endif

static __device__ __forceinline__ unsigned short f2bf(float x) {
  unsigned int u = __builtin_bit_cast(unsigned int, x);
  unsigned int r = (u + 0x7FFFu + ((u >> 16) & 1u)) >> 16;
  return (unsigned short)r;
}
static __device__ __forceinline__ float bf2f(unsigned short h) {
  unsigned int u = ((unsigned int)h) << 16;
  return __builtin_bit_cast(float, u);
}
static __device__ __forceinline__ void split2(float x, unsigned short& h, unsigned short& l) {
  h = f2bf(x);
  l = f2bf(x - bf2f(h));
}

// async global->LDS, 16B per lane; dest = wave-uniform base + lane*16
static __device__ __forceinline__ void glds16(const unsigned short* g, unsigned short* l) {
  __builtin_amdgcn_global_load_lds(
      (const __attribute__((address_space(1))) unsigned int*)g,
      (__attribute__((address_space(3))) unsigned int*)l,
      16, 0, 0);
}

// ---------------------------------------------------------------------------
// Merged pre-split: blocks 0..511 split the 4 weight matrices (hi/lo);
// blocks 512..4607 round x_cur / x_past to bf16 hi.
// ---------------------------------------------------------------------------
__global__ __launch_bounds__(256) void presplit(
    const float* __restrict__ wq, const float* __restrict__ wk,
    const float* __restrict__ wv, const float* __restrict__ wo,
    const float* __restrict__ xc, const float* __restrict__ xp,
    unsigned short* __restrict__ Wsp,
    unsigned short* __restrict__ Xchi, unsigned short* __restrict__ Xphi)
{
  const int bid = blockIdx.x;
  if (bid < 512) {
    const int mat = bid >> 7;
    const int chunk = ((bid & 127) * 256 + threadIdx.x) * 8;
    const float* src = (mat == 0) ? wq : (mat == 1) ? wk : (mat == 2) ? wv : wo;
    unsigned short* hi = Wsp + (size_t)mat * 524288;
    unsigned short* lo = hi + 262144;
    const f32x4 a = *reinterpret_cast<const f32x4*>(&src[chunk]);
    const f32x4 b = *reinterpret_cast<const f32x4*>(&src[chunk + 4]);
    u16x8 h8, l8;
#pragma unroll
    for (int i = 0; i < 4; ++i) { unsigned short hh, ll; split2(a[i], hh, ll); h8[i] = hh; l8[i] = ll; }
#pragma unroll
    for (int i = 0; i < 4; ++i) { unsigned short hh, ll; split2(b[i], hh, ll); h8[4 + i] = hh; l8[4 + i] = ll; }
    *reinterpret_cast<u16x8*>(&hi[chunk]) = h8;
    *reinterpret_cast<u16x8*>(&lo[chunk]) = l8;
  } else {
    const int i = bid - 512;              // 0..4095
    const int half = i >> 11;             // 0 = xc, 1 = xp
    const int ib = i & 2047;
    const float* src = half ? xp : xc;
    unsigned short* dst = half ? Xphi : Xchi;
    const int chunk = (ib * 256 + threadIdx.x) * 8;
    const f32x4 a = *reinterpret_cast<const f32x4*>(&src[chunk]);
    const f32x4 b = *reinterpret_cast<const f32x4*>(&src[chunk + 4]);
    u16x8 h8;
#pragma unroll
    for (int ii = 0; ii < 4; ++ii) h8[ii] = f2bf(a[ii]);
#pragma unroll
    for (int ii = 0; ii < 4; ++ii) h8[4 + ii] = f2bf(b[ii]);
    *reinterpret_cast<u16x8*>(&dst[chunk]) = h8;
  }
}

// ---------------------------------------------------------------------------
// Unified QKV projection from bf16 X (hi only). 100% global_load_lds staging,
// 2 MFMA per acc. z=0: Q (scale log2e/8) -> (B,H,T,Hd) hi.
// z=1: K -> (B,H,T,Hd) hi. z=2: V -> (B,H,Hd,T') hi, T' permuted per
// 16-group. (r17/r18 body, unchanged.)
// ---------------------------------------------------------------------------
__global__ __launch_bounds__(256, 4) void qkv_proj(
    const unsigned short* __restrict__ Xchi, const unsigned short* __restrict__ Xphi,
    const unsigned short* __restrict__ Wsp,
    const float* __restrict__ bq, const float* __restrict__ bk,
    const float* __restrict__ bv,
    unsigned short* __restrict__ Qhi, unsigned short* __restrict__ Khi,
    unsigned short* __restrict__ Vthi)
{
  __shared__ unsigned short Xh[128 * 64];
  __shared__ unsigned short Whi[64 * 64], Wlo[64 * 64];

  const int z = blockIdx.z;
  const unsigned short* Xsrc = (z == 0) ? Xchi : Xphi;
  const unsigned short* Wh_g = Wsp + (size_t)z * 524288;
  const unsigned short* Wl_g = Wh_g + 262144;
  const float* Bp = (z == 0) ? bq : (z == 1) ? bk : bv;
  const float scale = (z == 0) ? QSCALE : 1.0f;

  const int tid  = threadIdx.x;
  const int lane = tid & 63;
  const int wave = tid >> 6;
  const int g = lane >> 4, j = lane & 15;
  const int wm = (wave >> 1) * 64;
  const int wn = (wave & 1) * 32;
  const int row0 = blockIdx.x * 128;
  const int col0 = blockIdx.y * 64;

  f32x4 acc[4][2];
#pragma unroll
  for (int mi = 0; mi < 4; ++mi)
#pragma unroll
    for (int ni = 0; ni < 2; ++ni) acc[mi][ni] = (f32x4)0.f;

  const int xrow = wave * 32 + (lane >> 3);
  const int xkg  = (lane & 7) ^ ((lane >> 3) & 7);
  const unsigned short* srcX = Xsrc + (size_t)(row0 + xrow) * FEAT + xkg * 8;
  const int wrow = wave * 16 + (lane >> 3);
  const unsigned short* srcWh = Wh_g + (size_t)(col0 + wrow) * FEAT + xkg * 8;
  const unsigned short* srcWl = Wl_g + (size_t)(col0 + wrow) * FEAT + xkg * 8;

  for (int kt = 0; kt < FEAT; kt += 64) {
    __syncthreads();
#pragma unroll
    for (int c = 0; c < 4; ++c)
      glds16(srcX + kt + c * 4096, &Xh[(wave * 32 + c * 8) * 64]);
    glds16(srcWh + kt,        &Whi[(wave * 16) * 64]);
    glds16(srcWh + kt + 4096, &Whi[(wave * 16 + 8) * 64]);
    glds16(srcWl + kt,        &Wlo[(wave * 16) * 64]);
    glds16(srcWl + kt + 4096, &Wlo[(wave * 16 + 8) * 64]);
    asm volatile("s_waitcnt vmcnt(0)" ::: "memory");
    __syncthreads();

#pragma unroll
    for (int c = 0; c < 2; ++c) {
      const int koff = c * 32 + g * 8;
      s16x8 ah[4], bh[2], bl[2];
#pragma unroll
      for (int mi = 0; mi < 4; ++mi) {
        const int r = wm + mi * 16 + j;
        const int el = r * 64 + (koff ^ ((r & 7) << 3));
        ah[mi] = *reinterpret_cast<const s16x8*>(&Xh[el]);
      }
#pragma unroll
      for (int ni = 0; ni < 2; ++ni) {
        const int r = wn + ni * 16 + j;
        const int el = r * 64 + (koff ^ ((r & 7) << 3));
        bh[ni] = *reinterpret_cast<const s16x8*>(&Whi[el]);
        bl[ni] = *reinterpret_cast<const s16x8*>(&Wlo[el]);
      }
#pragma unroll
      for (int mi = 0; mi < 4; ++mi)
#pragma unroll
        for (int ni = 0; ni < 2; ++ni) {
          acc[mi][ni] = __builtin_amdgcn_mfma_f32_16x16x32_bf16(ah[mi], bh[ni], acc[mi][ni], 0, 0, 0);
          acc[mi][ni] = __builtin_amdgcn_mfma_f32_16x16x32_bf16(ah[mi], bl[ni], acc[mi][ni], 0, 0, 0);
        }
    }
  }

  if (z < 2) {
    unsigned short* Out = (z == 0) ? Qhi : Khi;
#pragma unroll
    for (int ni = 0; ni < 2; ++ni) {
      const int colc = col0 + wn + ni * 16 + j;
      const float bj = Bp[colc];
      const int h = colc >> 6, hd = colc & 63;
#pragma unroll
      for (int mi = 0; mi < 4; ++mi)
#pragma unroll
        for (int r = 0; r < 4; ++r) {
          const int rowc = row0 + wm + mi * 16 + (g << 2) + r;
          const int b = rowc >> 11, t = rowc & 2047;
          const float v = (acc[mi][ni][r] + bj) * scale;
          Out[(((size_t)b * NHEADS + h) * SEQ + t) * HD + hd] = f2bf(v);
        }
    }
  } else {
    __syncthreads();
#pragma unroll
    for (int ni = 0; ni < 2; ++ni) {
      const int hdl = wn + ni * 16 + j;
      const float bj = Bp[col0 + hdl];
#pragma unroll
      for (int mi = 0; mi < 4; ++mi)
#pragma unroll
        for (int r = 0; r < 4; ++r) {
          const int lt = wm + mi * 16 + (g << 2) + r;
          const float v = acc[mi][ni][r] + bj;
          const int el = lt * 64 + (hdl ^ ((lt & 7) << 3));
          Xh[el] = f2bf(v);
        }
    }
    __syncthreads();
    const int b = row0 >> 11, h = col0 >> 6;
    const int tbase = row0 & 2047;
#pragma unroll
    for (int c = 0; c < 4; ++c) {
      const int chunk = c * 256 + tid;
      const int hd = chunk >> 4;
      const int t0 = (chunk & 15) * 8;
      u16x8 vh;
#pragma unroll
      for (int i = 0; i < 8; ++i) {
        const int p = t0 + i;
        const int lt = (p & ~15) | ((p & 3) + (((p >> 2) & 1) << 3) + (((p >> 3) & 1) << 2));
        const int el = lt * 64 + (hd ^ ((lt & 7) << 3));
        vh[i] = Xh[el];
      }
      const size_t off = (((size_t)b * NHEADS + h) * HD + hd) * SEQ + tbase + t0;
      *reinterpret_cast<u16x8*>(&Vthi[off]) = vh;
    }
  }
}

// ---------------------------------------------------------------------------
// Output projection from bf16-hi AO: 2 MFMA per acc. 64-row tiles -> 1024
// blocks, 24KB LDS. (r18 body, unchanged.)
// ---------------------------------------------------------------------------
__global__ __launch_bounds__(256, 4) void out_proj(
    const unsigned short* __restrict__ AOhi,
    const unsigned short* __restrict__ Woh,  const unsigned short* __restrict__ Wol,
    const float* __restrict__ bias, float* __restrict__ out)
{
  __shared__ unsigned short Xh[64 * 64];
  __shared__ unsigned short Whi[64 * 64], Wlo[64 * 64];

  const int tid  = threadIdx.x;
  const int lane = tid & 63;
  const int wave = tid >> 6;
  const int g = lane >> 4, j = lane & 15;
  const int wm = (wave >> 1) * 32;
  const int wn = (wave & 1) * 32;
  const int row0 = blockIdx.x * 64;
  const int col0 = blockIdx.y * 64;

  f32x4 acc[2][2];
#pragma unroll
  for (int mi = 0; mi < 2; ++mi)
#pragma unroll
    for (int ni = 0; ni < 2; ++ni) acc[mi][ni] = (f32x4)0.f;

  const int arow = wave * 16 + (lane >> 3);
  const int akg  = (lane & 7) ^ ((lane >> 3) & 7);
  const unsigned short* srcA  = AOhi + (size_t)(row0 + arow) * FEAT + akg * 8;
  const unsigned short* srcWh = Woh + (size_t)(col0 + arow) * FEAT + akg * 8;
  const unsigned short* srcWl = Wol + (size_t)(col0 + arow) * FEAT + akg * 8;

  for (int kt = 0; kt < FEAT; kt += 64) {
    __syncthreads();
    glds16(srcA + kt,         &Xh[(wave * 16) * 64]);
    glds16(srcA + kt + 4096,  &Xh[(wave * 16 + 8) * 64]);
    glds16(srcWh + kt,        &Whi[(wave * 16) * 64]);
    glds16(srcWh + kt + 4096, &Whi[(wave * 16 + 8) * 64]);
    glds16(srcWl + kt,        &Wlo[(wave * 16) * 64]);
    glds16(srcWl + kt + 4096, &Wlo[(wave * 16 + 8) * 64]);
    asm volatile("s_waitcnt vmcnt(0)" ::: "memory");
    __syncthreads();

#pragma unroll
    for (int c = 0; c < 2; ++c) {
      const int koff = c * 32 + g * 8;
      s16x8 ah[2], bh[2], bl[2];
#pragma unroll
      for (int mi = 0; mi < 2; ++mi) {
        const int r = wm + mi * 16 + j;
        const int el = r * 64 + (koff ^ ((r & 7) << 3));
        ah[mi] = *reinterpret_cast<const s16x8*>(&Xh[el]);
      }
#pragma unroll
      for (int ni = 0; ni < 2; ++ni) {
        const int r = wn + ni * 16 + j;
        const int el = r * 64 + (koff ^ ((r & 7) << 3));
        bh[ni] = *reinterpret_cast<const s16x8*>(&Whi[el]);
        bl[ni] = *reinterpret_cast<const s16x8*>(&Wlo[el]);
      }
#pragma unroll
      for (int mi = 0; mi < 2; ++mi)
#pragma unroll
        for (int ni = 0; ni < 2; ++ni) {
          acc[mi][ni] = __builtin_amdgcn_mfma_f32_16x16x32_bf16(ah[mi], bh[ni], acc[mi][ni], 0, 0, 0);
          acc[mi][ni] = __builtin_amdgcn_mfma_f32_16x16x32_bf16(ah[mi], bl[ni], acc[mi][ni], 0, 0, 0);
        }
    }
  }

#pragma unroll
  for (int ni = 0; ni < 2; ++ni) {
    const int colc = col0 + wn + ni * 16 + j;
    const float bj = bias[colc];
#pragma unroll
    for (int mi = 0; mi < 2; ++mi)
#pragma unroll
      for (int r = 0; r < 4; ++r) {
        const int rowc = row0 + wm + mi * 16 + (g << 2) + r;
        out[(size_t)rowc * FEAT + colc] = acc[mi][ni][r] + bj;
      }
  }
}

// ---------------------------------------------------------------------------
// Flash attention: KVBLK=32, 3-buffer counted-vmcnt pipeline (vmcnt(2)),
// LDS 24.5KB -> 6 blocks/CU (24 waves). Same arithmetic sequence as r18
// (each former 32-key sub-tile is now one loop iteration). Pure-bf16 4-MFMA
// QK^T, PV hi-only with permuted-V, native exp2, deferred-l, conditional
// pm swap, AO hi-only epilogue.
// ---------------------------------------------------------------------------
__global__ __launch_bounds__(256, 6) void attn_pipe(
    const unsigned short* __restrict__ Qhi,
    const unsigned short* __restrict__ Khi,
    const unsigned short* __restrict__ Vthi,
    unsigned short* __restrict__ AOhi)
{
  __shared__ unsigned short Kh_s[3][2048];
  __shared__ unsigned short Vh_s[3][2048];
  __shared__ float bcast[4][32];

  const int tid = threadIdx.x, lane = tid & 63, wave = tid >> 6;
  const int hfl = lane >> 5;
  const int l31 = lane & 31;

  const int bid = blockIdx.x;
  const int swz = (bid & 7) * 64 + (bid >> 3);
  const int qt  = swz & 15;
  const int bh  = swz >> 4;
  const int b = bh >> 3, h = bh & 7;

  const int q0 = qt * 128 + wave * 32;
  const size_t kvbase = (size_t)bh * SEQ * HD;

  // Q B-fragments (bf16, pre-scaled by log2e/8 in proj)
  s16x8 qh[4];
  {
    const size_t qoff = kvbase + (size_t)(q0 + l31) * HD + hfl * 8;
#pragma unroll
    for (int c = 0; c < 4; ++c)
      qh[c] = *reinterpret_cast<const s16x8*>(&Qhi[qoff + c * 16]);
  }

  f32x16 oacc0 = (f32x16)0.f, oacc1 = (f32x16)0.f;
  float m = -INFINITY, lsum = 0.f;

  // staging source addresses (inverse-swizzled global); 1 K-glds + 1 V-glds
  // per thread per 32-key tile (4KB each).
  const int ck  = tid >> 3;
  const int ksl = (tid & 7) ^ (ck & 7);
  const unsigned short* sKh = Khi + kvbase + (size_t)ck * HD + ksl * 8;
  const int vr  = tid >> 3;
  const int vsl = (tid & 7) ^ (vr & 7);
  const int vhd = vr + (vsl >> 2) * 32;
  const int vk0 = (vsl & 3) * 8;
  const unsigned short* sVh = Vthi + kvbase + (size_t)vhd * SEQ + vk0;
  const int wq = wave * 512;

  const int krow = l31 * 64;
  const int ksw  = l31 & 7;

  auto stage = [&](int tt, int bi) {
    glds16(sKh + (size_t)tt * 32 * HD, &Kh_s[bi][wq]);
    glds16(sVh + tt * 32,              &Vh_s[bi][wq]);
  };

  // prologue: two tiles in flight
  stage(0, 0);
  stage(1, 1);

  const int NT = SEQ / 32;   // 64
  int cur = 0;
  for (int t = 0; t < NT; ++t) {
    if (t < NT - 1) {
      asm volatile("s_waitcnt vmcnt(2)" ::: "memory");
    } else {
      asm volatile("s_waitcnt vmcnt(0)" ::: "memory");
    }
    __syncthreads();
    if (t + 2 < NT) {
      int nb = cur + 2; if (nb >= 3) nb -= 3;
      stage(t + 2, nb);
    }
    __builtin_amdgcn_sched_barrier(0);

    s16x8 KH[4];
#pragma unroll
    for (int c = 0; c < 4; ++c) {
      const int idx = krow + ((((c << 1) | hfl)) ^ ksw) * 8;
      KH[c] = *reinterpret_cast<const s16x8*>(&Kh_s[cur][idx]);
    }

    // ---- S^T = K(bf16) Q(bf16)^T, single 4-chain ----
    f32x16 st = (f32x16)0.f;
    __builtin_amdgcn_s_setprio(1);
#pragma unroll
    for (int c = 0; c < 4; ++c)
      st = __builtin_amdgcn_mfma_f32_32x32x16_bf16(KH[c], qh[c], st, 0, 0, 0);
    __builtin_amdgcn_s_setprio(0);

    s16x8 V0h[2], V1h[2];
#pragma unroll
    for (int c = 0; c < 2; ++c) {
      const int i0 = krow + ((((c << 1) | hfl)) ^ ksw) * 8;
      const int i1 = krow + (((4 | (c << 1) | hfl)) ^ ksw) * 8;
      V0h[c] = *reinterpret_cast<const s16x8*>(&Vh_s[cur][i0]);
      V1h[c] = *reinterpret_cast<const s16x8*>(&Vh_s[cur][i1]);
    }

    const float a0 = fmaxf(fmaxf(st[0], st[1]), st[2]);
    const float a1 = fmaxf(fmaxf(st[3], st[4]), st[5]);
    const float a2 = fmaxf(fmaxf(st[6], st[7]), st[8]);
    const float a3 = fmaxf(fmaxf(st[9], st[10]), st[11]);
    const float a4 = fmaxf(fmaxf(st[12], st[13]), st[14]);
    const float pm = fmaxf(fmaxf(fmaxf(a0, a1), a2),
                           fmaxf(fmaxf(a3, a4), st[15]));

    if (__any(pm > m + 8.f)) {
      const float pmf  = fmaxf(pm, __shfl_xor(pm, 32));
      const float mnew = fmaxf(m, pmf);
      const float corr = EX2(m - mnew);
      m = mnew; lsum *= corr;
      if (lane < 32) bcast[wave][l31] = corr;
      f32x4 c4[4];
#pragma unroll
      for (int rq = 0; rq < 4; ++rq)
        c4[rq] = *reinterpret_cast<const f32x4*>(&bcast[wave][rq * 8 + hfl * 4]);
#pragma unroll
      for (int r = 0; r < 16; ++r) {
        const float cc = c4[r >> 2][r & 3];
        oacc0[r] *= cc; oacc1[r] *= cc;
      }
    }

#pragma unroll
    for (int r = 0; r < 16; ++r) st[r] = EX2(st[r] - m);
    {
      float s0 = (st[0] + st[1]) + (st[2] + st[3]);
      float s1 = (st[4] + st[5]) + (st[6] + st[7]);
      float s2 = (st[8] + st[9]) + (st[10] + st[11]);
      float s3 = (st[12] + st[13]) + (st[14] + st[15]);
      lsum += (s0 + s1) + (s2 + s3);
    }

    unsigned int wh[8];
#pragma unroll
    for (int p = 0; p < 8; ++p)
      asm("v_cvt_pk_bf16_f32 %0, %1, %2" : "=v"(wh[p]) : "v"(st[2 * p]), "v"(st[2 * p + 1]));
    const s16x8 pa0h = __builtin_bit_cast(s16x8, (u32x4){wh[0], wh[1], wh[2], wh[3]});
    const s16x8 pa1h = __builtin_bit_cast(s16x8, (u32x4){wh[4], wh[5], wh[6], wh[7]});

    __builtin_amdgcn_s_setprio(1);
    oacc0 = __builtin_amdgcn_mfma_f32_32x32x16_bf16(pa0h, V0h[0], oacc0, 0, 0, 0);
    oacc0 = __builtin_amdgcn_mfma_f32_32x32x16_bf16(pa1h, V0h[1], oacc0, 0, 0, 0);
    oacc1 = __builtin_amdgcn_mfma_f32_32x32x16_bf16(pa0h, V1h[0], oacc1, 0, 0, 0);
    oacc1 = __builtin_amdgcn_mfma_f32_32x32x16_bf16(pa1h, V1h[1], oacc1, 0, 0, 0);
    __builtin_amdgcn_s_setprio(0);

    cur += 1; if (cur >= 3) cur -= 3;
  }

  const float lf = lsum + __shfl_xor(lsum, 32);
  if (lane < 32) bcast[wave][l31] = 1.f / lf;
  __syncthreads();
  f32x4 i4[4];
#pragma unroll
  for (int rq = 0; rq < 4; ++rq)
    i4[rq] = *reinterpret_cast<const f32x4*>(&bcast[wave][rq * 8 + hfl * 4]);

#pragma unroll
  for (int r = 0; r < 16; ++r) {
    const int q = q0 + (r & 3) + 8 * (r >> 2) + 4 * hfl;
    const float inv = i4[r >> 2][r & 3];
    const size_t idx = ((size_t)b * SEQ + q) * FEAT + h * HD + l31;
    AOhi[idx]      = f2bf(oacc0[r] * inv);
    AOhi[idx + 32] = f2bf(oacc1[r] * inv);
  }
}

extern "C" void kernel_launch(void* const* d_in, const int* in_sizes, int n_in,
                              void* d_out, int out_size, void* d_ws, size_t ws_size,
                              hipStream_t stream) {
  const float* x_cur  = (const float*)d_in[0];
  const float* x_past = (const float*)d_in[1];
  const float* wq = (const float*)d_in[2];
  const float* bq = (const float*)d_in[3];
  const float* wk = (const float*)d_in[4];
  const float* bk = (const float*)d_in[5];
  const float* wv = (const float*)d_in[6];
  const float* bv = (const float*)d_in[7];
  const float* wo = (const float*)d_in[8];
  const float* bo = (const float*)d_in[9];
  float* out = (float*)d_out;

  const size_t n = (size_t)NROWS * FEAT;   // 4,194,304
  unsigned short* Qhi  = (unsigned short*)d_ws;
  unsigned short* Xchi = Qhi + n;
  unsigned short* Khi  = Qhi + 2 * n;
  unsigned short* Xphi = Qhi + 3 * n;
  unsigned short* Vthi = Qhi + 4 * n;
  unsigned short* Wsp  = Qhi + 5 * n;
  unsigned short* AOhi = Qhi + 6 * n;

  dim3 block(256);
  presplit<<<dim3(4608), block, 0, stream>>>(wq, wk, wv, wo, x_cur, x_past,
                                             Wsp, Xchi, Xphi);

  qkv_proj<<<dim3(NROWS / 128, FEAT / 64, 3), block, 0, stream>>>(
      Xchi, Xphi, Wsp, bq, bk, bv, Qhi, Khi, Vthi);

  attn_pipe<<<dim3(512), block, 0, stream>>>(Qhi, Khi, Vthi, AOhi);

  dim3 gout(NROWS / 64, FEAT / 64);
  out_proj<<<gout, block, 0, stream>>>(AOhi, Wsp + 3 * 524288,
                                       Wsp + 3 * 524288 + 262144, bo, out);
}

// Round 20
// 103.045 us; speedup vs baseline: 2.0914x; 2.0914x over previous
//
#include <hip/hip_runtime.h>
#include <math.h>

#define BATCH 4
#define SEQ 2048
#define FEAT 512
#define NHEADS 8
#define HD 64
#define NROWS (BATCH*SEQ)   // 8192
#define QSCALE 0.18033688011112042f   // log2(e)/8

typedef __attribute__((ext_vector_type(4)))  float f32x4;
typedef __attribute__((ext_vector_type(16))) float f32x16;
typedef __attribute__((ext_vector_type(8)))  short s16x8;
typedef __attribute__((ext_vector_type(8)))  unsigned short u16x8;
typedef __attribute__((ext_vector_type(4)))  unsigned int u32x4;

#if __has_builtin(__builtin_amdgcn_exp2f)
#define EX2(x) __builtin_amdgcn_exp2f(x)
#else
#define EX2(x) __expf((x) * 0.6931471805599453f)
#endif

static __device__ __forceinline__ unsigned short f2bf(float x) {
  unsigned int u = __builtin_bit_cast(unsigned int, x);
  unsigned int r = (u + 0x7FFFu + ((u >> 16) & 1u)) >> 16;
  return (unsigned short)r;
}
static __device__ __forceinline__ float bf2f(unsigned short h) {
  unsigned int u = ((unsigned int)h) << 16;
  return __builtin_bit_cast(float, u);
}
static __device__ __forceinline__ void split2(float x, unsigned short& h, unsigned short& l) {
  h = f2bf(x);
  l = f2bf(x - bf2f(h));
}

// async global->LDS, 16B per lane; dest = wave-uniform base + lane*16
static __device__ __forceinline__ void glds16(const unsigned short* g, unsigned short* l) {
  __builtin_amdgcn_global_load_lds(
      (const __attribute__((address_space(1))) unsigned int*)g,
      (__attribute__((address_space(3))) unsigned int*)l,
      16, 0, 0);
}

// ---------------------------------------------------------------------------
// Merged pre-split: blocks 0..511 split the 4 weight matrices (hi/lo);
// blocks 512..4607 round x_cur / x_past to bf16 hi.
// ---------------------------------------------------------------------------
__global__ __launch_bounds__(256) void presplit(
    const float* __restrict__ wq, const float* __restrict__ wk,
    const float* __restrict__ wv, const float* __restrict__ wo,
    const float* __restrict__ xc, const float* __restrict__ xp,
    unsigned short* __restrict__ Wsp,
    unsigned short* __restrict__ Xchi, unsigned short* __restrict__ Xphi)
{
  const int bid = blockIdx.x;
  if (bid < 512) {
    const int mat = bid >> 7;
    const int chunk = ((bid & 127) * 256 + threadIdx.x) * 8;
    const float* src = (mat == 0) ? wq : (mat == 1) ? wk : (mat == 2) ? wv : wo;
    unsigned short* hi = Wsp + (size_t)mat * 524288;
    unsigned short* lo = hi + 262144;
    const f32x4 a = *reinterpret_cast<const f32x4*>(&src[chunk]);
    const f32x4 b = *reinterpret_cast<const f32x4*>(&src[chunk + 4]);
    u16x8 h8, l8;
#pragma unroll
    for (int i = 0; i < 4; ++i) { unsigned short hh, ll; split2(a[i], hh, ll); h8[i] = hh; l8[i] = ll; }
#pragma unroll
    for (int i = 0; i < 4; ++i) { unsigned short hh, ll; split2(b[i], hh, ll); h8[4 + i] = hh; l8[4 + i] = ll; }
    *reinterpret_cast<u16x8*>(&hi[chunk]) = h8;
    *reinterpret_cast<u16x8*>(&lo[chunk]) = l8;
  } else {
    const int i = bid - 512;              // 0..4095
    const int half = i >> 11;             // 0 = xc, 1 = xp
    const int ib = i & 2047;
    const float* src = half ? xp : xc;
    unsigned short* dst = half ? Xphi : Xchi;
    const int chunk = (ib * 256 + threadIdx.x) * 8;
    const f32x4 a = *reinterpret_cast<const f32x4*>(&src[chunk]);
    const f32x4 b = *reinterpret_cast<const f32x4*>(&src[chunk + 4]);
    u16x8 h8;
#pragma unroll
    for (int ii = 0; ii < 4; ++ii) h8[ii] = f2bf(a[ii]);
#pragma unroll
    for (int ii = 0; ii < 4; ++ii) h8[4 + ii] = f2bf(b[ii]);
    *reinterpret_cast<u16x8*>(&dst[chunk]) = h8;
  }
}

// ---------------------------------------------------------------------------
// Unified QKV projection from bf16 X (hi only). 100% global_load_lds staging,
// 2 MFMA per acc. z=0: Q (scale log2e/8) -> (B,H,T,Hd) hi.
// z=1: K -> (B,H,T,Hd) hi. z=2: V -> (B,H,Hd,T') hi, T' permuted per
// 16-group.
// ---------------------------------------------------------------------------
__global__ __launch_bounds__(256, 4) void qkv_proj(
    const unsigned short* __restrict__ Xchi, const unsigned short* __restrict__ Xphi,
    const unsigned short* __restrict__ Wsp,
    const float* __restrict__ bq, const float* __restrict__ bk,
    const float* __restrict__ bv,
    unsigned short* __restrict__ Qhi, unsigned short* __restrict__ Khi,
    unsigned short* __restrict__ Vthi)
{
  __shared__ unsigned short Xh[128 * 64];
  __shared__ unsigned short Whi[64 * 64], Wlo[64 * 64];

  const int z = blockIdx.z;
  const unsigned short* Xsrc = (z == 0) ? Xchi : Xphi;
  const unsigned short* Wh_g = Wsp + (size_t)z * 524288;
  const unsigned short* Wl_g = Wh_g + 262144;
  const float* Bp = (z == 0) ? bq : (z == 1) ? bk : bv;
  const float scale = (z == 0) ? QSCALE : 1.0f;

  const int tid  = threadIdx.x;
  const int lane = tid & 63;
  const int wave = tid >> 6;
  const int g = lane >> 4, j = lane & 15;
  const int wm = (wave >> 1) * 64;
  const int wn = (wave & 1) * 32;
  const int row0 = blockIdx.x * 128;
  const int col0 = blockIdx.y * 64;

  f32x4 acc[4][2];
#pragma unroll
  for (int mi = 0; mi < 4; ++mi)
#pragma unroll
    for (int ni = 0; ni < 2; ++ni) acc[mi][ni] = (f32x4)0.f;

  const int xrow = wave * 32 + (lane >> 3);
  const int xkg  = (lane & 7) ^ ((lane >> 3) & 7);
  const unsigned short* srcX = Xsrc + (size_t)(row0 + xrow) * FEAT + xkg * 8;
  const int wrow = wave * 16 + (lane >> 3);
  const unsigned short* srcWh = Wh_g + (size_t)(col0 + wrow) * FEAT + xkg * 8;
  const unsigned short* srcWl = Wl_g + (size_t)(col0 + wrow) * FEAT + xkg * 8;

  for (int kt = 0; kt < FEAT; kt += 64) {
    __syncthreads();
#pragma unroll
    for (int c = 0; c < 4; ++c)
      glds16(srcX + kt + c * 4096, &Xh[(wave * 32 + c * 8) * 64]);
    glds16(srcWh + kt,        &Whi[(wave * 16) * 64]);
    glds16(srcWh + kt + 4096, &Whi[(wave * 16 + 8) * 64]);
    glds16(srcWl + kt,        &Wlo[(wave * 16) * 64]);
    glds16(srcWl + kt + 4096, &Wlo[(wave * 16 + 8) * 64]);
    asm volatile("s_waitcnt vmcnt(0)" ::: "memory");
    __syncthreads();

#pragma unroll
    for (int c = 0; c < 2; ++c) {
      const int koff = c * 32 + g * 8;
      s16x8 ah[4], bh[2], bl[2];
#pragma unroll
      for (int mi = 0; mi < 4; ++mi) {
        const int r = wm + mi * 16 + j;
        const int el = r * 64 + (koff ^ ((r & 7) << 3));
        ah[mi] = *reinterpret_cast<const s16x8*>(&Xh[el]);
      }
#pragma unroll
      for (int ni = 0; ni < 2; ++ni) {
        const int r = wn + ni * 16 + j;
        const int el = r * 64 + (koff ^ ((r & 7) << 3));
        bh[ni] = *reinterpret_cast<const s16x8*>(&Whi[el]);
        bl[ni] = *reinterpret_cast<const s16x8*>(&Wlo[el]);
      }
#pragma unroll
      for (int mi = 0; mi < 4; ++mi)
#pragma unroll
        for (int ni = 0; ni < 2; ++ni) {
          acc[mi][ni] = __builtin_amdgcn_mfma_f32_16x16x32_bf16(ah[mi], bh[ni], acc[mi][ni], 0, 0, 0);
          acc[mi][ni] = __builtin_amdgcn_mfma_f32_16x16x32_bf16(ah[mi], bl[ni], acc[mi][ni], 0, 0, 0);
        }
    }
  }

  if (z < 2) {
    unsigned short* Out = (z == 0) ? Qhi : Khi;
#pragma unroll
    for (int ni = 0; ni < 2; ++ni) {
      const int colc = col0 + wn + ni * 16 + j;
      const float bj = Bp[colc];
      const int h = colc >> 6, hd = colc & 63;
#pragma unroll
      for (int mi = 0; mi < 4; ++mi)
#pragma unroll
        for (int r = 0; r < 4; ++r) {
          const int rowc = row0 + wm + mi * 16 + (g << 2) + r;
          const int b = rowc >> 11, t = rowc & 2047;
          const float v = (acc[mi][ni][r] + bj) * scale;
          Out[(((size_t)b * NHEADS + h) * SEQ + t) * HD + hd] = f2bf(v);
        }
    }
  } else {
    __syncthreads();
#pragma unroll
    for (int ni = 0; ni < 2; ++ni) {
      const int hdl = wn + ni * 16 + j;
      const float bj = Bp[col0 + hdl];
#pragma unroll
      for (int mi = 0; mi < 4; ++mi)
#pragma unroll
        for (int r = 0; r < 4; ++r) {
          const int lt = wm + mi * 16 + (g << 2) + r;
          const float v = acc[mi][ni][r] + bj;
          const int el = lt * 64 + (hdl ^ ((lt & 7) << 3));
          Xh[el] = f2bf(v);
        }
    }
    __syncthreads();
    const int b = row0 >> 11, h = col0 >> 6;
    const int tbase = row0 & 2047;
#pragma unroll
    for (int c = 0; c < 4; ++c) {
      const int chunk = c * 256 + tid;
      const int hd = chunk >> 4;
      const int t0 = (chunk & 15) * 8;
      u16x8 vh;
#pragma unroll
      for (int i = 0; i < 8; ++i) {
        const int p = t0 + i;
        const int lt = (p & ~15) | ((p & 3) + (((p >> 2) & 1) << 3) + (((p >> 3) & 1) << 2));
        const int el = lt * 64 + (hd ^ ((lt & 7) << 3));
        vh[i] = Xh[el];
      }
      const size_t off = (((size_t)b * NHEADS + h) * HD + hd) * SEQ + tbase + t0;
      *reinterpret_cast<u16x8*>(&Vthi[off]) = vh;
    }
  }
}

// ---------------------------------------------------------------------------
// Output projection from bf16-hi AO: 2 MFMA per acc. 64-row tiles -> 1024
// blocks, 24KB LDS.
// ---------------------------------------------------------------------------
__global__ __launch_bounds__(256, 4) void out_proj(
    const unsigned short* __restrict__ AOhi,
    const unsigned short* __restrict__ Woh,  const unsigned short* __restrict__ Wol,
    const float* __restrict__ bias, float* __restrict__ out)
{
  __shared__ unsigned short Xh[64 * 64];
  __shared__ unsigned short Whi[64 * 64], Wlo[64 * 64];

  const int tid  = threadIdx.x;
  const int lane = tid & 63;
  const int wave = tid >> 6;
  const int g = lane >> 4, j = lane & 15;
  const int wm = (wave >> 1) * 32;
  const int wn = (wave & 1) * 32;
  const int row0 = blockIdx.x * 64;
  const int col0 = blockIdx.y * 64;

  f32x4 acc[2][2];
#pragma unroll
  for (int mi = 0; mi < 2; ++mi)
#pragma unroll
    for (int ni = 0; ni < 2; ++ni) acc[mi][ni] = (f32x4)0.f;

  const int arow = wave * 16 + (lane >> 3);
  const int akg  = (lane & 7) ^ ((lane >> 3) & 7);
  const unsigned short* srcA  = AOhi + (size_t)(row0 + arow) * FEAT + akg * 8;
  const unsigned short* srcWh = Woh + (size_t)(col0 + arow) * FEAT + akg * 8;
  const unsigned short* srcWl = Wol + (size_t)(col0 + arow) * FEAT + akg * 8;

  for (int kt = 0; kt < FEAT; kt += 64) {
    __syncthreads();
    glds16(srcA + kt,         &Xh[(wave * 16) * 64]);
    glds16(srcA + kt + 4096,  &Xh[(wave * 16 + 8) * 64]);
    glds16(srcWh + kt,        &Whi[(wave * 16) * 64]);
    glds16(srcWh + kt + 4096, &Whi[(wave * 16 + 8) * 64]);
    glds16(srcWl + kt,        &Wlo[(wave * 16) * 64]);
    glds16(srcWl + kt + 4096, &Wlo[(wave * 16 + 8) * 64]);
    asm volatile("s_waitcnt vmcnt(0)" ::: "memory");
    __syncthreads();

#pragma unroll
    for (int c = 0; c < 2; ++c) {
      const int koff = c * 32 + g * 8;
      s16x8 ah[2], bh[2], bl[2];
#pragma unroll
      for (int mi = 0; mi < 2; ++mi) {
        const int r = wm + mi * 16 + j;
        const int el = r * 64 + (koff ^ ((r & 7) << 3));
        ah[mi] = *reinterpret_cast<const s16x8*>(&Xh[el]);
      }
#pragma unroll
      for (int ni = 0; ni < 2; ++ni) {
        const int r = wn + ni * 16 + j;
        const int el = r * 64 + (koff ^ ((r & 7) << 3));
        bh[ni] = *reinterpret_cast<const s16x8*>(&Whi[el]);
        bl[ni] = *reinterpret_cast<const s16x8*>(&Wlo[el]);
      }
#pragma unroll
      for (int mi = 0; mi < 2; ++mi)
#pragma unroll
        for (int ni = 0; ni < 2; ++ni) {
          acc[mi][ni] = __builtin_amdgcn_mfma_f32_16x16x32_bf16(ah[mi], bh[ni], acc[mi][ni], 0, 0, 0);
          acc[mi][ni] = __builtin_amdgcn_mfma_f32_16x16x32_bf16(ah[mi], bl[ni], acc[mi][ni], 0, 0, 0);
        }
    }
  }

#pragma unroll
  for (int ni = 0; ni < 2; ++ni) {
    const int colc = col0 + wn + ni * 16 + j;
    const float bj = bias[colc];
#pragma unroll
    for (int mi = 0; mi < 2; ++mi)
#pragma unroll
      for (int r = 0; r < 4; ++r) {
        const int rowc = row0 + wm + mi * 16 + (g << 2) + r;
        out[(size_t)rowc * FEAT + colc] = acc[mi][ni][r] + bj;
      }
  }
}

// ---------------------------------------------------------------------------
// Flash attention (r18 body, known-good): 3-buffer counted-vmcnt LDS
// pipeline, KVBLK=64, pure-bf16 4-MFMA QK^T, PV hi-only with permuted-V,
// native exp2, deferred-l, conditional pm swap, AO hi-only epilogue.
// Grid 512 = 2 blocks/CU (grid-limited decomposition: 2048 waves total).
// ---------------------------------------------------------------------------
__global__ __launch_bounds__(256, 3) void attn_pipe(
    const unsigned short* __restrict__ Qhi,
    const unsigned short* __restrict__ Khi,
    const unsigned short* __restrict__ Vthi,
    unsigned short* __restrict__ AOhi)
{
  __shared__ unsigned short Kh_s[3][4096];
  __shared__ unsigned short Vh_s[3][4096];
  __shared__ float bcast[4][32];

  const int tid = threadIdx.x, lane = tid & 63, wave = tid >> 6;
  const int hfl = lane >> 5;
  const int l31 = lane & 31;

  const int bid = blockIdx.x;
  const int swz = (bid & 7) * 64 + (bid >> 3);
  const int qt  = swz & 15;
  const int bh  = swz >> 4;
  const int b = bh >> 3, h = bh & 7;

  const int q0 = qt * 128 + wave * 32;
  const size_t kvbase = (size_t)bh * SEQ * HD;

  s16x8 qh[4];
  {
    const size_t qoff = kvbase + (size_t)(q0 + l31) * HD + hfl * 8;
#pragma unroll
    for (int c = 0; c < 4; ++c)
      qh[c] = *reinterpret_cast<const s16x8*>(&Qhi[qoff + c * 16]);
  }

  f32x16 oacc0 = (f32x16)0.f, oacc1 = (f32x16)0.f;
  float m = -INFINITY, lsum = 0.f;

  const int ck  = tid >> 3;
  const int ksl = (tid & 7) ^ (ck & 7);
  const unsigned short* sKh = Khi + kvbase + (size_t)ck * HD + ksl * 8;
  const int vr  = tid >> 3;
  const int vsl = (tid & 7) ^ (vr & 7);
  const int vhd = vr + (vsl >> 2) * 32;
  const int vk0 = (vsl & 3) * 8;
  const unsigned short* sVh = Vthi + kvbase + (size_t)vhd * SEQ + vk0;
  const int wq = wave * 512;

  const int krow = l31 * 64;
  const int ksw  = l31 & 7;

  auto stage = [&](int tt, int bi) {
    const size_t ko = (size_t)tt * 64 * HD;
    const int    vo = tt * 64;
    glds16(sKh + ko,           &Kh_s[bi][wq]);
    glds16(sKh + ko + 32 * HD, &Kh_s[bi][2048 + wq]);
    glds16(sVh + vo,           &Vh_s[bi][wq]);
    glds16(sVh + vo + 32,      &Vh_s[bi][2048 + wq]);
  };

  stage(0, 0);
  stage(1, 1);

  const int NT = SEQ / 64;   // 32
  int cur = 0;
  for (int t = 0; t < NT; ++t) {
    if (t < NT - 1) {
      asm volatile("s_waitcnt vmcnt(4)" ::: "memory");
    } else {
      asm volatile("s_waitcnt vmcnt(0)" ::: "memory");
    }
    __syncthreads();
    if (t + 2 < NT) {
      int nb = cur + 2; if (nb >= 3) nb -= 3;
      stage(t + 2, nb);
    }
    __builtin_amdgcn_sched_barrier(0);

#pragma unroll
    for (int sub = 0; sub < 2; ++sub) {
      const int sb = sub * 2048;

      s16x8 KH[4];
#pragma unroll
      for (int c = 0; c < 4; ++c) {
        const int idx = sb + krow + ((((c << 1) | hfl)) ^ ksw) * 8;
        KH[c] = *reinterpret_cast<const s16x8*>(&Kh_s[cur][idx]);
      }

      f32x16 st = (f32x16)0.f;
      __builtin_amdgcn_s_setprio(1);
#pragma unroll
      for (int c = 0; c < 4; ++c)
        st = __builtin_amdgcn_mfma_f32_32x32x16_bf16(KH[c], qh[c], st, 0, 0, 0);
      __builtin_amdgcn_s_setprio(0);

      s16x8 V0h[2], V1h[2];
#pragma unroll
      for (int c = 0; c < 2; ++c) {
        const int i0 = sb + krow + ((((c << 1) | hfl)) ^ ksw) * 8;
        const int i1 = sb + krow + (((4 | (c << 1) | hfl)) ^ ksw) * 8;
        V0h[c] = *reinterpret_cast<const s16x8*>(&Vh_s[cur][i0]);
        V1h[c] = *reinterpret_cast<const s16x8*>(&Vh_s[cur][i1]);
      }

      const float a0 = fmaxf(fmaxf(st[0], st[1]), st[2]);
      const float a1 = fmaxf(fmaxf(st[3], st[4]), st[5]);
      const float a2 = fmaxf(fmaxf(st[6], st[7]), st[8]);
      const float a3 = fmaxf(fmaxf(st[9], st[10]), st[11]);
      const float a4 = fmaxf(fmaxf(st[12], st[13]), st[14]);
      const float pm = fmaxf(fmaxf(fmaxf(a0, a1), a2),
                             fmaxf(fmaxf(a3, a4), st[15]));

      if (__any(pm > m + 8.f)) {
        const float pmf  = fmaxf(pm, __shfl_xor(pm, 32));
        const float mnew = fmaxf(m, pmf);
        const float corr = EX2(m - mnew);
        m = mnew; lsum *= corr;
        if (lane < 32) bcast[wave][l31] = corr;
        f32x4 c4[4];
#pragma unroll
        for (int rq = 0; rq < 4; ++rq)
          c4[rq] = *reinterpret_cast<const f32x4*>(&bcast[wave][rq * 8 + hfl * 4]);
#pragma unroll
        for (int r = 0; r < 16; ++r) {
          const float cc = c4[r >> 2][r & 3];
          oacc0[r] *= cc; oacc1[r] *= cc;
        }
      }

#pragma unroll
      for (int r = 0; r < 16; ++r) st[r] = EX2(st[r] - m);
      {
        float s0 = (st[0] + st[1]) + (st[2] + st[3]);
        float s1 = (st[4] + st[5]) + (st[6] + st[7]);
        float s2 = (st[8] + st[9]) + (st[10] + st[11]);
        float s3 = (st[12] + st[13]) + (st[14] + st[15]);
        lsum += (s0 + s1) + (s2 + s3);
      }

      unsigned int wh[8];
#pragma unroll
      for (int p = 0; p < 8; ++p)
        asm("v_cvt_pk_bf16_f32 %0, %1, %2" : "=v"(wh[p]) : "v"(st[2 * p]), "v"(st[2 * p + 1]));
      const s16x8 pa0h = __builtin_bit_cast(s16x8, (u32x4){wh[0], wh[1], wh[2], wh[3]});
      const s16x8 pa1h = __builtin_bit_cast(s16x8, (u32x4){wh[4], wh[5], wh[6], wh[7]});

      __builtin_amdgcn_s_setprio(1);
      oacc0 = __builtin_amdgcn_mfma_f32_32x32x16_bf16(pa0h, V0h[0], oacc0, 0, 0, 0);
      oacc0 = __builtin_amdgcn_mfma_f32_32x32x16_bf16(pa1h, V0h[1], oacc0, 0, 0, 0);
      oacc1 = __builtin_amdgcn_mfma_f32_32x32x16_bf16(pa0h, V1h[0], oacc1, 0, 0, 0);
      oacc1 = __builtin_amdgcn_mfma_f32_32x32x16_bf16(pa1h, V1h[1], oacc1, 0, 0, 0);
      __builtin_amdgcn_s_setprio(0);
    }

    cur += 1; if (cur >= 3) cur -= 3;
  }

  const float lf = lsum + __shfl_xor(lsum, 32);
  if (lane < 32) bcast[wave][l31] = 1.f / lf;
  __syncthreads();
  f32x4 i4[4];
#pragma unroll
  for (int rq = 0; rq < 4; ++rq)
    i4[rq] = *reinterpret_cast<const f32x4*>(&bcast[wave][rq * 8 + hfl * 4]);

#pragma unroll
  for (int r = 0; r < 16; ++r) {
    const int q = q0 + (r & 3) + 8 * (r >> 2) + 4 * hfl;
    const float inv = i4[r >> 2][r & 3];
    const size_t idx = ((size_t)b * SEQ + q) * FEAT + h * HD + l31;
    AOhi[idx]      = f2bf(oacc0[r] * inv);
    AOhi[idx + 32] = f2bf(oacc1[r] * inv);
  }
}

extern "C" void kernel_launch(void* const* d_in, const int* in_sizes, int n_in,
                              void* d_out, int out_size, void* d_ws, size_t ws_size,
                              hipStream_t stream) {
  const float* x_cur  = (const float*)d_in[0];
  const float* x_past = (const float*)d_in[1];
  const float* wq = (const float*)d_in[2];
  const float* bq = (const float*)d_in[3];
  const float* wk = (const float*)d_in[4];
  const float* bk = (const float*)d_in[5];
  const float* wv = (const float*)d_in[6];
  const float* bv = (const float*)d_in[7];
  const float* wo = (const float*)d_in[8];
  const float* bo = (const float*)d_in[9];
  float* out = (float*)d_out;

  const size_t n = (size_t)NROWS * FEAT;   // 4,194,304
  unsigned short* Qhi  = (unsigned short*)d_ws;
  unsigned short* Xchi = Qhi + n;
  unsigned short* Khi  = Qhi + 2 * n;
  unsigned short* Xphi = Qhi + 3 * n;
  unsigned short* Vthi = Qhi + 4 * n;
  unsigned short* Wsp  = Qhi + 5 * n;
  unsigned short* AOhi = Qhi + 6 * n;

  dim3 block(256);
  presplit<<<dim3(4608), block, 0, stream>>>(wq, wk, wv, wo, x_cur, x_past,
                                             Wsp, Xchi, Xphi);

  qkv_proj<<<dim3(NROWS / 128, FEAT / 64, 3), block, 0, stream>>>(
      Xchi, Xphi, Wsp, bq, bk, bv, Qhi, Khi, Vthi);

  attn_pipe<<<dim3(512), block, 0, stream>>>(Qhi, Khi, Vthi, AOhi);

  dim3 gout(NROWS / 64, FEAT / 64);
  out_proj<<<gout, block, 0, stream>>>(AOhi, Wsp + 3 * 524288,
                                       Wsp + 3 * 524288 + 262144, bo, out);
}